// Round 3
// baseline (470.904 us; speedup 1.0000x reference)
//
#include <hip/hip_runtime.h>

#define B_   8
#define C_   128
#define H_   128
#define W_   128
#define HW_  16384

typedef short v8s __attribute__((ext_vector_type(8)));
typedef float v4f __attribute__((ext_vector_type(4)));

#define CSTR 56            // LDS column stride (bytes): 14 words, odd period -> no 4-way conflicts

__device__ __forceinline__ float bf2f(unsigned short u) {
  unsigned int v = ((unsigned int)u) << 16;
  float f; __builtin_memcpy(&f, &v, 4); return f;
}
__device__ __forceinline__ unsigned short f2us(float f) {
  unsigned int u; __builtin_memcpy(&u, &f, 4);
  u += 0x7fffu + ((u >> 16) & 1u);           // RNE
  return (unsigned short)(u >> 16);
}

// ---------------- pack weights into MFMA A-fragment order --------------------
__global__ __launch_bounds__(256) void pack_w(const float* __restrict__ w,
                                              unsigned short* __restrict__ pack,
                                              int G) {
  int idx = blockIdx.x * 256 + threadIdx.x;
  if (idx >= 20480 * G) return;
  int j  = idx & 7;
  int l  = (idx >> 3) & 63;
  int g  = (idx >> 9) % G;
  int t2 = idx / (512 * G);
  int pp = t2 % 5;
  int cc = t2 / 5;
  int oc = g * 16 + (l & 15);
  int kk = ((l >> 4) << 3) + j;
  int ic = (cc << 4) + (kk & 15);
  int rs = pp * 2 + (kk >> 4);
  float v = (rs < 9) ? w[(oc * C_ + ic) * 9 + rs] : 0.f;
  pack[idx] = f2us(v);
}

// ---------------- transpose x: fp32 [b][c][i][j] -> bf16 [b][i][j][c] --------
__global__ __launch_bounds__(256) void transpose_x(const float* __restrict__ x,
                                                   unsigned short* __restrict__ xt) {
  __shared__ alignas(16) unsigned short t[32 * 132];
  const int j0 = blockIdx.x * 32, i = blockIdx.y, b = blockIdx.z;
  const int tid = threadIdx.x;
  for (int e = tid; e < 128 * 32; e += 256) {
    int c = e >> 5, jj = e & 31;
    float v = x[((b * C_ + c) * H_ + i) * W_ + j0 + jj];
    t[jj * 132 + c] = f2us(v);
  }
  __syncthreads();
  for (int e = tid; e < 32 * 32; e += 256) {
    int c4 = (e & 31) << 2, jj = e >> 5;
    uint2 v = *(const uint2*)&t[jj * 132 + c4];
    *(uint2*)(xt + ((b * H_ + i) * W_ + j0 + jj) * C_ + c4) = v;
  }
}

// ---------------- implicit-GEMM conv via MFMA --------------------------------
// XCD-aware swizzle: blockIdx.x & 7 == XCD; each XCD owns contiguous 16-row
// strips (b-major within the strip) so halo re-reads hit that XCD's L2.
// MODE 0: plain bf16 store (offset conv). MODE 1: +bias+relu+BN partials.
template <int MODE, int G>
__global__ __launch_bounds__(256) void conv_gemm(const unsigned short* __restrict__ xt,
                                                 const unsigned short* __restrict__ pack,
                                                 const float* __restrict__ bias,
                                                 unsigned short* __restrict__ outp,
                                                 float* __restrict__ ps) {
  __shared__ uint4 raw4[(3 * 130 * CSTR) / 16];
  __shared__ float bs1[128], bs2[128];
  char* raw = (char*)raw4;

  const int nb = blockIdx.x;
  int b, i, mt;
  {
    int xcd = nb & 7, r = nb >> 3;
    if (MODE == 0) { b = r >> 5; mt = (r >> 4) & 1; i = xcd * 16 + (r & 15); }
    else           { b = r >> 4; mt = 0;            i = xcd * 16 + (r & 15); }
  }
  const int tid  = threadIdx.x;
  const int lane = tid & 63, wid = tid >> 6;
  const int q = lane >> 4, n = lane & 15;
  const int wm = wid & 1, wn = wid >> 1;

  if (MODE == 1 && tid < 128) { bs1[tid] = 0.f; bs2[tid] = 0.f; }

  int boff[5];
#pragma unroll
  for (int pp = 0; pp < 5; ++pp) {
    int rs = pp * 2 + (q >> 1);
    if (rs > 8) rs = 8;                               // pad half: A is zero there
    int r = (rs >= 6) ? 2 : ((rs >= 3) ? 1 : 0);
    int s = rs - r * 3;
    boff[pp] = (r * 130 + s) * CSTR + (q & 1) * 16;
  }
  const int pcol = (wn * 64 + n) * CSTR;

  v4f acc[4][4];
#pragma unroll
  for (int a = 0; a < 4; ++a)
#pragma unroll
    for (int c = 0; c < 4; ++c) acc[a][c] = (v4f){0.f, 0.f, 0.f, 0.f};

  const v8s* packv = (const v8s*)pack;
  const int gbase = mt * 8 + wm * 4;

  for (int cc = 0; cc < 8; ++cc) {
    __syncthreads();
    for (int u = tid; u < 780; u += 256) {
      int half = u & 1, rc = u >> 1;
      int r = rc / 130, c = rc - r * 130;
      int ii = i + r - 1, jj = c - 1;
      uint4 v = {0u, 0u, 0u, 0u};
      if ((unsigned)ii < 128u && (unsigned)jj < 128u)
        v = *(const uint4*)(xt + ((b * H_ + ii) * W_ + jj) * C_ + cc * 16 + half * 8);
      *(uint4*)(raw + rc * CSTR + half * 16) = v;
    }
    __syncthreads();

    v8s Acur[4];
    {
      const v8s* ap = packv + ((cc * 5 + 0) * G + gbase) * 64 + lane;
#pragma unroll
      for (int fm = 0; fm < 4; ++fm) Acur[fm] = ap[fm * 64];
    }
#pragma unroll
    for (int pp = 0; pp < 5; ++pp) {
      v8s Anxt[4];
      if (pp < 4) {
        const v8s* ap = packv + ((cc * 5 + pp + 1) * G + gbase) * 64 + lane;
#pragma unroll
        for (int fm = 0; fm < 4; ++fm) Anxt[fm] = ap[fm * 64];
      }
      v8s Bf[4];
#pragma unroll
      for (int fn = 0; fn < 4; ++fn)
        Bf[fn] = *(const v8s*)(raw + boff[pp] + pcol + fn * (16 * CSTR));
#pragma unroll
      for (int fm = 0; fm < 4; ++fm) {
#pragma unroll
        for (int fn = 0; fn < 4; ++fn)
          acc[fm][fn] = __builtin_amdgcn_mfma_f32_16x16x32_bf16(Acur[fm], Bf[fn],
                                                                acc[fm][fn], 0, 0, 0);
      }
      if (pp < 4) {
#pragma unroll
        for (int fm = 0; fm < 4; ++fm) Acur[fm] = Anxt[fm];
      }
    }
  }

  const int OC = G * 16;
  const int ob = (b * OC + mt * 128 + wm * 64) * HW_ + i * W_ + wn * 64;

  if (MODE == 0) {
#pragma unroll
    for (int fm = 0; fm < 4; ++fm)
#pragma unroll
      for (int fn = 0; fn < 4; ++fn)
#pragma unroll
        for (int rr = 0; rr < 4; ++rr)
          outp[ob + (fm * 16 + q * 4 + rr) * HW_ + fn * 16 + n] = f2us(acc[fm][fn][rr]);
  } else {
    float bv[4][4], s1a[4][4], s2a[4][4];
#pragma unroll
    for (int fm = 0; fm < 4; ++fm)
#pragma unroll
      for (int rr = 0; rr < 4; ++rr) {
        bv[fm][rr] = bias[wm * 64 + fm * 16 + q * 4 + rr];
        s1a[fm][rr] = 0.f; s2a[fm][rr] = 0.f;
      }
#pragma unroll
    for (int fm = 0; fm < 4; ++fm)
#pragma unroll
      for (int fn = 0; fn < 4; ++fn)
#pragma unroll
        for (int rr = 0; rr < 4; ++rr) {
          float v = acc[fm][fn][rr] + bv[fm][rr];
          v = fmaxf(v, 0.f);
          outp[ob + (fm * 16 + q * 4 + rr) * HW_ + fn * 16 + n] = f2us(v);
          s1a[fm][rr] += v; s2a[fm][rr] += v * v;
        }
#pragma unroll
    for (int fm = 0; fm < 4; ++fm)
#pragma unroll
      for (int rr = 0; rr < 4; ++rr) {
        float s1 = s1a[fm][rr], s2 = s2a[fm][rr];
#pragma unroll
        for (int m = 1; m < 16; m <<= 1) {
          s1 += __shfl_xor(s1, m);
          s2 += __shfl_xor(s2, m);
        }
        if (n == 0) {
          atomicAdd(&bs1[wm * 64 + fm * 16 + q * 4 + rr], s1);
          atomicAdd(&bs2[wm * 64 + fm * 16 + q * 4 + rr], s2);
        }
      }
    __syncthreads();
    if (tid < 128) {
      ps[nb * 128 + tid]          = bs1[tid];
      ps[131072 + nb * 128 + tid] = bs2[tid];
    }
  }
}

// ---------------- deform + fused transpose -----------------------------------
__global__ __launch_bounds__(256) void deform_t(const float* __restrict__ x,
                                                const unsigned short* __restrict__ offs,
                                                unsigned short* __restrict__ xofft) {
  __shared__ alignas(16) unsigned short t[128 * 132];
  const int i = blockIdx.x, b = blockIdx.y;
  const int tid = threadIdx.x;
  for (int e = tid; e < 16384; e += 256) {
    int c = e >> 7, j = e & 127;
    int qpix = (i << 7) + j;
    int oidx = (b << 22) + (c << 15) + 2 * qpix;     // quirky reshape semantics
    unsigned int pr = *(const unsigned int*)(offs + oidx);
    float oy = bf2f((unsigned short)(pr & 0xffffu));
    float ox = bf2f((unsigned short)(pr >> 16));
    float yc = fminf(fmaxf(oy + (float)i, 0.f), 127.f);
    float xc = fminf(fmaxf(ox + (float)j, 0.f), 127.f);
    float y0f = floorf(yc), y1f = ceilf(yc);
    float x0f = floorf(xc), x1f = ceilf(xc);
    int y0 = (int)y0f, y1 = (int)y1f, x0 = (int)x0f, x1 = (int)x1f;
    const float* img = x + ((b * C_ + c) << 14);
    float v_lt = img[y0 * W_ + x0];
    float v_rb = img[y1 * W_ + x1];
    float v_lb = img[y0 * W_ + x1];
    float v_rt = img[y1 * W_ + x0];
    float dy = yc - y0f, dx = xc - x0f;
    float v_t = v_lt + (v_rt - v_lt) * dy;
    float v_b = v_lb + (v_rb - v_lb) * dy;
    float o   = v_t + (v_b - v_t) * dx;
    t[j * 132 + c] = f2us(o);
  }
  __syncthreads();
  for (int e = tid; e < 4096; e += 256) {
    int c4 = (e & 31) << 2, j = e >> 5;
    uint2 v = *(const uint2*)&t[j * 132 + c4];
    *(uint2*)(xofft + ((b * H_ + i) * W_ + j) * C_ + c4) = v;
  }
}

// ---------------- BN finalize: fold stats into scale/shift -------------------
__global__ __launch_bounds__(256) void bn_finalize(const float* __restrict__ ps,
                                                   const float* __restrict__ gamma,
                                                   const float* __restrict__ beta,
                                                   float* __restrict__ stats) {
  const int c = blockIdx.x, tid = threadIdx.x;
  float s1 = 0.f, s2 = 0.f;
  for (int k = tid; k < 1024; k += 256) {
    s1 += ps[k * 128 + c];
    s2 += ps[131072 + k * 128 + c];
  }
#pragma unroll
  for (int m = 32; m > 0; m >>= 1) {
    s1 += __shfl_down(s1, m);
    s2 += __shfl_down(s2, m);
  }
  __shared__ float l1[4], l2[4];
  int wid = tid >> 6;
  if ((tid & 63) == 0) { l1[wid] = s1; l2[wid] = s2; }
  __syncthreads();
  if (tid == 0) {
    s1 = l1[0] + l1[1] + l1[2] + l1[3];
    s2 = l2[0] + l2[1] + l2[2] + l2[3];
    const float invn = 1.f / 131072.f;
    float mean = s1 * invn;
    float var  = s2 * invn - mean * mean;
    float inv  = rsqrtf(var + 1e-5f);
    float sc = gamma[c] * inv;
    stats[c]       = sc;
    stats[128 + c] = beta[c] - mean * sc;
  }
}

// ---------------- BN apply: bf16 y -> fp32 out -------------------------------
__global__ __launch_bounds__(256) void bn_apply(const unsigned short* __restrict__ y,
                                                const float* __restrict__ stats,
                                                float* __restrict__ out) {
  int gid = blockIdx.x * 256 + threadIdx.x;
  int base = gid << 3;
  int c = (base >> 14) & 127;
  float sc = stats[c], sh = stats[128 + c];
  uint4 u = *(const uint4*)(y + base);
  const unsigned short* us = (const unsigned short*)&u;
  float4 o0, o1;
  o0.x = bf2f(us[0]) * sc + sh;  o0.y = bf2f(us[1]) * sc + sh;
  o0.z = bf2f(us[2]) * sc + sh;  o0.w = bf2f(us[3]) * sc + sh;
  o1.x = bf2f(us[4]) * sc + sh;  o1.y = bf2f(us[5]) * sc + sh;
  o1.z = bf2f(us[6]) * sc + sh;  o1.w = bf2f(us[7]) * sc + sh;
  ((float4*)out)[gid * 2]     = o0;
  ((float4*)out)[gid * 2 + 1] = o1;
}

// ---------------- launch -----------------------------------------------------
extern "C" void kernel_launch(void* const* d_in, const int* in_sizes, int n_in,
                              void* d_out, int out_size, void* d_ws, size_t ws_size,
                              hipStream_t stream) {
  const float* x      = (const float*)d_in[0];
  const float* w_off  = (const float*)d_in[1];
  const float* w_conv = (const float*)d_in[2];
  const float* b_conv = (const float*)d_in[3];
  const float* gamma  = (const float*)d_in[4];
  const float* beta   = (const float*)d_in[5];
  float* out = (float*)d_out;

  char* ws = (char*)d_ws;
  unsigned short* x_t    = (unsigned short*)ws;        // 32M, dead after conv_off
  unsigned short* xoff_t = (unsigned short*)ws;        // aliases x_t
  unsigned short* offs = (unsigned short*)(ws + 33554432);  // 64M
  unsigned short* yws  = (unsigned short*)(ws + 33554432);  // aliases offs lo half
  float* ps    = (float*)(ws + 67108864);
  float* stats = (float*)(ws + 68157440);
  unsigned short* pack_off  = (unsigned short*)(ws + 100663296);
  unsigned short* pack_main = (unsigned short*)(ws + 101318656);

  pack_w<<<80 * 16, 256, 0, stream>>>(w_off, pack_off, 16);
  pack_w<<<80 * 8, 256, 0, stream>>>(w_conv, pack_main, 8);
  transpose_x<<<dim3(4, 128, 8), 256, 0, stream>>>(x, x_t);
  conv_gemm<0, 16><<<2048, 256, 0, stream>>>(x_t, pack_off, nullptr, offs, nullptr);
  deform_t<<<dim3(128, 8), 256, 0, stream>>>(x, offs, xoff_t);
  conv_gemm<1, 8><<<1024, 256, 0, stream>>>(xoff_t, pack_main, b_conv, yws, ps);
  bn_finalize<<<128, 256, 0, stream>>>(ps, gamma, beta, stats);
  bn_apply<<<8192, 256, 0, stream>>>(yws, stats, out);
}

// Round 4
// 469.791 us; speedup vs baseline: 1.0024x; 1.0024x over previous
//
#include <hip/hip_runtime.h>

#define B_   8
#define C_   128
#define H_   128
#define W_   128
#define HW_  16384

typedef short v8s __attribute__((ext_vector_type(8)));
typedef float v4f __attribute__((ext_vector_type(4)));

#define CSTR 56            // LDS column stride (bytes): 14 words -> conflict-free (round 3: SQ_LDS_BANK_CONFLICT=0)

__device__ __forceinline__ float bf2f(unsigned short u) {
  unsigned int v = ((unsigned int)u) << 16;
  float f; __builtin_memcpy(&f, &v, 4); return f;
}
__device__ __forceinline__ unsigned short f2us(float f) {
  unsigned int u; __builtin_memcpy(&u, &f, 4);
  u += 0x7fffu + ((u >> 16) & 1u);           // RNE
  return (unsigned short)(u >> 16);
}

// ---------------- pack weights into MFMA A-fragment order --------------------
__global__ __launch_bounds__(256) void pack_w(const float* __restrict__ w,
                                              unsigned short* __restrict__ pack,
                                              int G) {
  int idx = blockIdx.x * 256 + threadIdx.x;
  if (idx >= 20480 * G) return;
  int j  = idx & 7;
  int l  = (idx >> 3) & 63;
  int g  = (idx >> 9) % G;
  int t2 = idx / (512 * G);
  int pp = t2 % 5;
  int cc = t2 / 5;
  int oc = g * 16 + (l & 15);
  int kk = ((l >> 4) << 3) + j;
  int ic = (cc << 4) + (kk & 15);
  int rs = pp * 2 + (kk >> 4);
  float v = (rs < 9) ? w[(oc * C_ + ic) * 9 + rs] : 0.f;
  pack[idx] = f2us(v);
}

// ---------------- transpose x: fp32 [b][c][i][j] -> bf16 [b][i][j][c] --------
__global__ __launch_bounds__(256) void transpose_x(const float* __restrict__ x,
                                                   unsigned short* __restrict__ xt) {
  __shared__ alignas(16) unsigned short t[32 * 132];
  const int j0 = blockIdx.x * 32, i = blockIdx.y, b = blockIdx.z;
  const int tid = threadIdx.x;
  for (int e = tid; e < 128 * 32; e += 256) {
    int c = e >> 5, jj = e & 31;
    float v = x[((b * C_ + c) * H_ + i) * W_ + j0 + jj];
    t[jj * 132 + c] = f2us(v);
  }
  __syncthreads();
  for (int e = tid; e < 32 * 32; e += 256) {
    int c4 = (e & 31) << 2, jj = e >> 5;
    uint2 v = *(const uint2*)&t[jj * 132 + c4];
    *(uint2*)(xt + ((b * H_ + i) * W_ + j0 + jj) * C_ + c4) = v;
  }
}

// ---------------- implicit-GEMM conv via MFMA, register-pipelined staging ----
// Per cc: barrier -> ds_write prefetched R -> barrier -> issue loads for cc+1
// (drained at NEXT iteration's first barrier, i.e. hidden under the MFMA phase)
// MODE 0: plain bf16 store (offset conv). MODE 1: +bias+relu+BN partials.
template <int MODE, int G>
__global__ __launch_bounds__(256) void conv_gemm(const unsigned short* __restrict__ xt,
                                                 const unsigned short* __restrict__ pack,
                                                 const float* __restrict__ bias,
                                                 unsigned short* __restrict__ outp,
                                                 float* __restrict__ ps) {
  __shared__ uint4 raw4[(3 * 130 * CSTR) / 16];
  __shared__ float bs1[128], bs2[128];
  char* raw = (char*)raw4;

  const int nb = blockIdx.x;
  int b, i, mt;
  {
    int xcd = nb & 7, r = nb >> 3;
    if (MODE == 0) { b = r >> 5; mt = (r >> 4) & 1; i = xcd * 16 + (r & 15); }
    else           { b = r >> 4; mt = 0;            i = xcd * 16 + (r & 15); }
  }
  const int tid  = threadIdx.x;
  const int lane = tid & 63, wid = tid >> 6;
  const int q = lane >> 4, n = lane & 15;
  const int wm = wid & 1, wn = wid >> 1;

  if (MODE == 1 && tid < 128) { bs1[tid] = 0.f; bs2[tid] = 0.f; }

  // ---- staging slot descriptors (fixed per thread across cc) ----
  const unsigned short* gp[4];
  int lof[4];
  bool sval[4], sact[4];
  uint4 R[4];
#pragma unroll
  for (int t = 0; t < 4; ++t) {
    int u = tid + t * 256;
    sact[t] = (u < 780);
    int half = u & 1, rc = u >> 1;
    int r = rc / 130, c = rc - r * 130;
    int ii = i + r - 1, jj = c - 1;
    sval[t] = sact[t] && ((unsigned)ii < 128u) && ((unsigned)jj < 128u);
    gp[t] = xt + ((size_t)((b * H_ + ii) * W_ + jj)) * C_ + half * 8;
    lof[t] = rc * CSTR + half * 16;
    R[t] = (uint4){0u, 0u, 0u, 0u};
  }
#pragma unroll
  for (int t = 0; t < 4; ++t) if (sval[t]) R[t] = *(const uint4*)(gp[t]);

  int boff[5];
#pragma unroll
  for (int pp = 0; pp < 5; ++pp) {
    int rs = pp * 2 + (q >> 1);
    if (rs > 8) rs = 8;                               // pad half: A is zero there
    int r = (rs >= 6) ? 2 : ((rs >= 3) ? 1 : 0);
    int s = rs - r * 3;
    boff[pp] = (r * 130 + s) * CSTR + (q & 1) * 16;
  }
  const int pcol = (wn * 64 + n) * CSTR;

  v4f acc[4][4];
#pragma unroll
  for (int a = 0; a < 4; ++a)
#pragma unroll
    for (int c = 0; c < 4; ++c) acc[a][c] = (v4f){0.f, 0.f, 0.f, 0.f};

  const v8s* packv = (const v8s*)pack;
  const int gbase = mt * 8 + wm * 4;

  // A fragments carried across cc (prefetched one (cc,pp)-step ahead)
  v8s Acur[4];
  {
    const v8s* ap = packv + (0 * G + gbase) * 64 + lane;
#pragma unroll
    for (int fm = 0; fm < 4; ++fm) Acur[fm] = ap[fm * 64];
  }

  for (int cc = 0; cc < 8; ++cc) {
    __syncthreads();                                  // drains prefetched loads
#pragma unroll
    for (int t = 0; t < 4; ++t)
      if (sact[t]) *(uint4*)(raw + lof[t]) = R[t];
    __syncthreads();
    if (cc < 7) {
#pragma unroll
      for (int t = 0; t < 4; ++t)
        if (sval[t]) R[t] = *(const uint4*)(gp[t] + (cc + 1) * 16);
    }

#pragma unroll
    for (int pp = 0; pp < 5; ++pp) {
      v8s Anxt[4];
      const bool havenext = (pp < 4) || (cc < 7);
      if (havenext) {
        int ncc = (pp < 4) ? cc : cc + 1;
        int npp = (pp < 4) ? pp + 1 : 0;
        const v8s* ap = packv + ((ncc * 5 + npp) * G + gbase) * 64 + lane;
#pragma unroll
        for (int fm = 0; fm < 4; ++fm) Anxt[fm] = ap[fm * 64];
      }
      v8s Bf[4];
#pragma unroll
      for (int fn = 0; fn < 4; ++fn)
        Bf[fn] = *(const v8s*)(raw + boff[pp] + pcol + fn * (16 * CSTR));
#pragma unroll
      for (int fm = 0; fm < 4; ++fm) {
#pragma unroll
        for (int fn = 0; fn < 4; ++fn)
          acc[fm][fn] = __builtin_amdgcn_mfma_f32_16x16x32_bf16(Acur[fm], Bf[fn],
                                                                acc[fm][fn], 0, 0, 0);
      }
      if (havenext) {
#pragma unroll
        for (int fm = 0; fm < 4; ++fm) Acur[fm] = Anxt[fm];
      }
    }
  }

  const int OC = G * 16;
  const int ob = (b * OC + mt * 128 + wm * 64) * HW_ + i * W_ + wn * 64;

  if (MODE == 0) {
#pragma unroll
    for (int fm = 0; fm < 4; ++fm)
#pragma unroll
      for (int fn = 0; fn < 4; ++fn)
#pragma unroll
        for (int rr = 0; rr < 4; ++rr)
          outp[ob + (fm * 16 + q * 4 + rr) * HW_ + fn * 16 + n] = f2us(acc[fm][fn][rr]);
  } else {
    float bv[4][4], s1a[4][4], s2a[4][4];
#pragma unroll
    for (int fm = 0; fm < 4; ++fm)
#pragma unroll
      for (int rr = 0; rr < 4; ++rr) {
        bv[fm][rr] = bias[wm * 64 + fm * 16 + q * 4 + rr];
        s1a[fm][rr] = 0.f; s2a[fm][rr] = 0.f;
      }
#pragma unroll
    for (int fm = 0; fm < 4; ++fm)
#pragma unroll
      for (int fn = 0; fn < 4; ++fn)
#pragma unroll
        for (int rr = 0; rr < 4; ++rr) {
          float v = acc[fm][fn][rr] + bv[fm][rr];
          v = fmaxf(v, 0.f);
          outp[ob + (fm * 16 + q * 4 + rr) * HW_ + fn * 16 + n] = f2us(v);
          s1a[fm][rr] += v; s2a[fm][rr] += v * v;
        }
#pragma unroll
    for (int fm = 0; fm < 4; ++fm)
#pragma unroll
      for (int rr = 0; rr < 4; ++rr) {
        float s1 = s1a[fm][rr], s2 = s2a[fm][rr];
#pragma unroll
        for (int m = 1; m < 16; m <<= 1) {
          s1 += __shfl_xor(s1, m);
          s2 += __shfl_xor(s2, m);
        }
        if (n == 0) {
          atomicAdd(&bs1[wm * 64 + fm * 16 + q * 4 + rr], s1);
          atomicAdd(&bs2[wm * 64 + fm * 16 + q * 4 + rr], s2);
        }
      }
    __syncthreads();
    if (tid < 128) {
      ps[nb * 128 + tid]          = bs1[tid];
      ps[131072 + nb * 128 + tid] = bs2[tid];
    }
  }
}

// ---------------- deform + fused transpose -----------------------------------
__global__ __launch_bounds__(256) void deform_t(const float* __restrict__ x,
                                                const unsigned short* __restrict__ offs,
                                                unsigned short* __restrict__ xofft) {
  __shared__ alignas(16) unsigned short t[128 * 132];
  const int i = blockIdx.x, b = blockIdx.y;
  const int tid = threadIdx.x;
  for (int e = tid; e < 16384; e += 256) {
    int c = e >> 7, j = e & 127;
    int qpix = (i << 7) + j;
    int oidx = (b << 22) + (c << 15) + 2 * qpix;     // quirky reshape semantics
    unsigned int pr = *(const unsigned int*)(offs + oidx);
    float oy = bf2f((unsigned short)(pr & 0xffffu));
    float ox = bf2f((unsigned short)(pr >> 16));
    float yc = fminf(fmaxf(oy + (float)i, 0.f), 127.f);
    float xc = fminf(fmaxf(ox + (float)j, 0.f), 127.f);
    float y0f = floorf(yc), y1f = ceilf(yc);
    float x0f = floorf(xc), x1f = ceilf(xc);
    int y0 = (int)y0f, y1 = (int)y1f, x0 = (int)x0f, x1 = (int)x1f;
    const float* img = x + ((b * C_ + c) << 14);
    float v_lt = img[y0 * W_ + x0];
    float v_rb = img[y1 * W_ + x1];
    float v_lb = img[y0 * W_ + x1];
    float v_rt = img[y1 * W_ + x0];
    float dy = yc - y0f, dx = xc - x0f;
    float v_t = v_lt + (v_rt - v_lt) * dy;
    float v_b = v_lb + (v_rb - v_lb) * dy;
    float o   = v_t + (v_b - v_t) * dx;
    t[j * 132 + c] = f2us(o);
  }
  __syncthreads();
  for (int e = tid; e < 4096; e += 256) {
    int c4 = (e & 31) << 2, j = e >> 5;
    uint2 v = *(const uint2*)&t[j * 132 + c4];
    *(uint2*)(xofft + ((b * H_ + i) * W_ + j) * C_ + c4) = v;
  }
}

// ---------------- BN finalize: fold stats into scale/shift -------------------
__global__ __launch_bounds__(256) void bn_finalize(const float* __restrict__ ps,
                                                   const float* __restrict__ gamma,
                                                   const float* __restrict__ beta,
                                                   float* __restrict__ stats) {
  const int c = blockIdx.x, tid = threadIdx.x;
  float s1 = 0.f, s2 = 0.f;
  for (int k = tid; k < 1024; k += 256) {
    s1 += ps[k * 128 + c];
    s2 += ps[131072 + k * 128 + c];
  }
#pragma unroll
  for (int m = 32; m > 0; m >>= 1) {
    s1 += __shfl_down(s1, m);
    s2 += __shfl_down(s2, m);
  }
  __shared__ float l1[4], l2[4];
  int wid = tid >> 6;
  if ((tid & 63) == 0) { l1[wid] = s1; l2[wid] = s2; }
  __syncthreads();
  if (tid == 0) {
    s1 = l1[0] + l1[1] + l1[2] + l1[3];
    s2 = l2[0] + l2[1] + l2[2] + l2[3];
    const float invn = 1.f / 131072.f;
    float mean = s1 * invn;
    float var  = s2 * invn - mean * mean;
    float inv  = rsqrtf(var + 1e-5f);
    float sc = gamma[c] * inv;
    stats[c]       = sc;
    stats[128 + c] = beta[c] - mean * sc;
  }
}

// ---------------- BN apply: bf16 y -> fp32 out -------------------------------
__global__ __launch_bounds__(256) void bn_apply(const unsigned short* __restrict__ y,
                                                const float* __restrict__ stats,
                                                float* __restrict__ out) {
  int gid = blockIdx.x * 256 + threadIdx.x;
  int base = gid << 3;
  int c = (base >> 14) & 127;
  float sc = stats[c], sh = stats[128 + c];
  uint4 u = *(const uint4*)(y + base);
  const unsigned short* us = (const unsigned short*)&u;
  float4 o0, o1;
  o0.x = bf2f(us[0]) * sc + sh;  o0.y = bf2f(us[1]) * sc + sh;
  o0.z = bf2f(us[2]) * sc + sh;  o0.w = bf2f(us[3]) * sc + sh;
  o1.x = bf2f(us[4]) * sc + sh;  o1.y = bf2f(us[5]) * sc + sh;
  o1.z = bf2f(us[6]) * sc + sh;  o1.w = bf2f(us[7]) * sc + sh;
  ((float4*)out)[gid * 2]     = o0;
  ((float4*)out)[gid * 2 + 1] = o1;
}

// ---------------- launch -----------------------------------------------------
extern "C" void kernel_launch(void* const* d_in, const int* in_sizes, int n_in,
                              void* d_out, int out_size, void* d_ws, size_t ws_size,
                              hipStream_t stream) {
  const float* x      = (const float*)d_in[0];
  const float* w_off  = (const float*)d_in[1];
  const float* w_conv = (const float*)d_in[2];
  const float* b_conv = (const float*)d_in[3];
  const float* gamma  = (const float*)d_in[4];
  const float* beta   = (const float*)d_in[5];
  float* out = (float*)d_out;

  char* ws = (char*)d_ws;
  unsigned short* x_t    = (unsigned short*)ws;        // 32M, dead after conv_off
  unsigned short* xoff_t = (unsigned short*)ws;        // aliases x_t
  unsigned short* offs = (unsigned short*)(ws + 33554432);  // 64M
  unsigned short* yws  = (unsigned short*)(ws + 33554432);  // aliases offs lo half
  float* ps    = (float*)(ws + 67108864);
  float* stats = (float*)(ws + 68157440);
  unsigned short* pack_off  = (unsigned short*)(ws + 100663296);
  unsigned short* pack_main = (unsigned short*)(ws + 101318656);

  pack_w<<<80 * 16, 256, 0, stream>>>(w_off, pack_off, 16);
  pack_w<<<80 * 8, 256, 0, stream>>>(w_conv, pack_main, 8);
  transpose_x<<<dim3(4, 128, 8), 256, 0, stream>>>(x, x_t);
  conv_gemm<0, 16><<<2048, 256, 0, stream>>>(x_t, pack_off, nullptr, offs, nullptr);
  deform_t<<<dim3(128, 8), 256, 0, stream>>>(x, offs, xoff_t);
  conv_gemm<1, 8><<<1024, 256, 0, stream>>>(xoff_t, pack_main, b_conv, yws, ps);
  bn_finalize<<<128, 256, 0, stream>>>(ps, gamma, beta, stats);
  bn_apply<<<8192, 256, 0, stream>>>(yws, stats, out);
}

// Round 5
// 332.201 us; speedup vs baseline: 1.4175x; 1.4142x over previous
//
#include <hip/hip_runtime.h>

#define B_   8
#define C_   128
#define H_   128
#define W_   128
#define HW_  16384

typedef short v8s __attribute__((ext_vector_type(8)));
typedef float v4f __attribute__((ext_vector_type(4)));

// LDS B-tile: 3 rows x 130 px-slots x 32B (16ch bf16). Row stride 4160 B.
#define ROWB 4160

__device__ __forceinline__ float bf2f(unsigned short u) {
  unsigned int v = ((unsigned int)u) << 16;
  float f; __builtin_memcpy(&f, &v, 4); return f;
}
__device__ __forceinline__ unsigned short f2us(float f) {
  unsigned int u; __builtin_memcpy(&u, &f, 4);
  u += 0x7fffu + ((u >> 16) & 1u);           // RNE
  return (unsigned short)(u >> 16);
}

// ---------------- pack weights into MFMA A-fragment order + zero scratch -----
__global__ __launch_bounds__(256) void pack_w(const float* __restrict__ w,
                                              unsigned short* __restrict__ pack,
                                              uint4* __restrict__ zb, int G) {
  if (blockIdx.x == 0) zb[threadIdx.x] = (uint4){0u, 0u, 0u, 0u};  // 4 KB zeros
  int idx = blockIdx.x * 256 + threadIdx.x;
  if (idx >= 20480 * G) return;
  int j  = idx & 7;
  int l  = (idx >> 3) & 63;
  int g  = (idx >> 9) % G;
  int t2 = idx / (512 * G);
  int pp = t2 % 5;
  int cc = t2 / 5;
  int oc = g * 16 + (l & 15);
  int kk = ((l >> 4) << 3) + j;
  int ic = (cc << 4) + (kk & 15);
  int rs = pp * 2 + (kk >> 4);
  float v = (rs < 9) ? w[(oc * C_ + ic) * 9 + rs] : 0.f;
  pack[idx] = f2us(v);
}

// ------- transpose x: fp32 [b][c][i][j] -> bf16 [b][cg][i][j][16c] -----------
__global__ __launch_bounds__(256) void transpose_x(const float* __restrict__ x,
                                                   unsigned short* __restrict__ xt) {
  __shared__ alignas(16) unsigned short t[32 * 132];
  const int j0 = blockIdx.x * 32, i = blockIdx.y, b = blockIdx.z;
  const int tid = threadIdx.x;
  for (int e = tid; e < 128 * 32; e += 256) {
    int c = e >> 5, jj = e & 31;
    float v = x[((b * C_ + c) * H_ + i) * W_ + j0 + jj];
    t[jj * 132 + c] = f2us(v);
  }
  __syncthreads();
  for (int f = tid; f < 1024; f += 256) {          // coalesced: 4 thr = 32B of one px
    int cg = f >> 7, g = f & 127;
    int j = g >> 2, c4 = (g & 3) << 2;
    uint2 v = *(const uint2*)&t[j * 132 + cg * 16 + c4];
    *(uint2*)(xt + ((size_t)(b * 8 + cg) * HW_ + i * W_ + j0 + j) * 16 + c4) = v;
  }
}

// ---------------- implicit-GEMM conv via MFMA, global_load_lds staging -------
// Per cc: barrier -> 3 async DMA chunks/wave into LDS -> barrier -> MFMA phase.
// MODE 0: plain bf16 store (offset conv). MODE 1: +bias+relu+BN partials.
template <int MODE, int G>
__global__ __launch_bounds__(256) void conv_gemm(const unsigned short* __restrict__ xt,
                                                 const unsigned short* __restrict__ pack,
                                                 const float* __restrict__ bias,
                                                 const char* __restrict__ zb,
                                                 unsigned short* __restrict__ outp,
                                                 float* __restrict__ ps) {
  __shared__ alignas(16) char rawb[3 * ROWB];      // 12480 B
  __shared__ float bs1[128], bs2[128];

  const int nb = blockIdx.x;
  int b, i, mt;
  {
    int xcd = nb & 7, r = nb >> 3;
    if (MODE == 0) { b = r >> 5; mt = (r >> 4) & 1; i = xcd * 16 + (r & 15); }
    else           { b = r >> 4; mt = 0;            i = xcd * 16 + (r & 15); }
  }
  const int tid  = threadIdx.x;
  const int lane = tid & 63, wid = tid >> 6;
  const int q = lane >> 4, n = lane & 15;
  const int wm = wid & 1, wn = wid >> 1;

  if (MODE == 1 && tid < 128) { bs1[tid] = 0.f; bs2[tid] = 0.f; }
  // halo-edge slots (px -1 / 128) are always zero: write once
  if (tid < 12) {
    int r = tid >> 2, rem = tid & 3, side = rem >> 1, h = rem & 1;
    *(uint4*)(rawb + r * ROWB + (side ? 129 * 32 : 0) + h * 16) = (uint4){0u,0u,0u,0u};
  }

  // per-pp LDS base: rs -> (row r, col s), 32B px stride, (q&1) picks 16B half
  int boff[5];
#pragma unroll
  for (int pp = 0; pp < 5; ++pp) {
    int rs = pp * 2 + (q >> 1);
    if (rs > 8) rs = 8;                            // pad half: A is zero there
    int r = (rs >= 6) ? 2 : ((rs >= 3) ? 1 : 0);
    int s = rs - r * 3;
    boff[pp] = r * ROWB + s * 32 + (q & 1) * 16;
  }
  const int pcol = (wn * 64 + n) * 32;

  v4f acc[4][4];
#pragma unroll
  for (int a = 0; a < 4; ++a)
#pragma unroll
    for (int c = 0; c < 4; ++c) acc[a][c] = (v4f){0.f, 0.f, 0.f, 0.f};

  const v8s* packv = (const v8s*)pack;
  const int gbase = mt * 8 + wm * 4;

  v8s Acur[4];
  {
    const v8s* ap = packv + (0 * G + gbase) * 64 + lane;
#pragma unroll
    for (int fm = 0; fm < 4; ++fm) Acur[fm] = ap[fm * 64];
  }

  for (int cc = 0; cc < 8; ++cc) {
    __syncthreads();                               // prev compute done
    // stage 3 halo rows (12 x 1KB chunks; wave w -> chunks 3w..3w+2)
    const char* ccbase = (const char*)xt + (size_t)(b * 8 + cc) * (HW_ * 32);
#pragma unroll
    for (int t = 0; t < 3; ++t) {
      int c = wid * 3 + t, r = c >> 2, k = c & 3;
      int ii = i + r - 1;
      const char* src = ((unsigned)ii < 128u)
                          ? ccbase + ii * 4096 + k * 1024 + lane * 16
                          : zb + lane * 16;
      __builtin_amdgcn_global_load_lds(
          (const __attribute__((address_space(1))) unsigned int*)src,
          (__attribute__((address_space(3))) unsigned int*)(rawb + r * ROWB + 32 + k * 1024),
          16, 0, 0);
    }
    __syncthreads();                               // vmcnt drain: DMA visible

#pragma unroll
    for (int pp = 0; pp < 5; ++pp) {
      v8s Anxt[4];
      const bool havenext = (pp < 4) || (cc < 7);
      if (havenext) {
        int ncc = (pp < 4) ? cc : cc + 1;
        int npp = (pp < 4) ? pp + 1 : 0;
        const v8s* ap = packv + ((ncc * 5 + npp) * G + gbase) * 64 + lane;
#pragma unroll
        for (int fm = 0; fm < 4; ++fm) Anxt[fm] = ap[fm * 64];
      }
      v8s Bf[4];
#pragma unroll
      for (int fn = 0; fn < 4; ++fn)
        Bf[fn] = *(const v8s*)(rawb + boff[pp] + pcol + fn * 512);
#pragma unroll
      for (int fm = 0; fm < 4; ++fm) {
#pragma unroll
        for (int fn = 0; fn < 4; ++fn)
          acc[fm][fn] = __builtin_amdgcn_mfma_f32_16x16x32_bf16(Acur[fm], Bf[fn],
                                                                acc[fm][fn], 0, 0, 0);
      }
      if (havenext) {
#pragma unroll
        for (int fm = 0; fm < 4; ++fm) Acur[fm] = Anxt[fm];
      }
    }
  }

  const int OC = G * 16;
  const int ob = (b * OC + mt * 128 + wm * 64) * HW_ + i * W_ + wn * 64;

  if (MODE == 0) {
#pragma unroll
    for (int fm = 0; fm < 4; ++fm)
#pragma unroll
      for (int fn = 0; fn < 4; ++fn)
#pragma unroll
        for (int rr = 0; rr < 4; ++rr)
          outp[ob + (fm * 16 + q * 4 + rr) * HW_ + fn * 16 + n] = f2us(acc[fm][fn][rr]);
  } else {
    float bv[4][4], s1a[4][4], s2a[4][4];
#pragma unroll
    for (int fm = 0; fm < 4; ++fm)
#pragma unroll
      for (int rr = 0; rr < 4; ++rr) {
        bv[fm][rr] = bias[wm * 64 + fm * 16 + q * 4 + rr];
        s1a[fm][rr] = 0.f; s2a[fm][rr] = 0.f;
      }
#pragma unroll
    for (int fm = 0; fm < 4; ++fm)
#pragma unroll
      for (int fn = 0; fn < 4; ++fn)
#pragma unroll
        for (int rr = 0; rr < 4; ++rr) {
          float v = acc[fm][fn][rr] + bv[fm][rr];
          v = fmaxf(v, 0.f);
          outp[ob + (fm * 16 + q * 4 + rr) * HW_ + fn * 16 + n] = f2us(v);
          s1a[fm][rr] += v; s2a[fm][rr] += v * v;
        }
#pragma unroll
    for (int fm = 0; fm < 4; ++fm)
#pragma unroll
      for (int rr = 0; rr < 4; ++rr) {
        float s1 = s1a[fm][rr], s2 = s2a[fm][rr];
#pragma unroll
        for (int m = 1; m < 16; m <<= 1) {
          s1 += __shfl_xor(s1, m);
          s2 += __shfl_xor(s2, m);
        }
        if (n == 0) {
          atomicAdd(&bs1[wm * 64 + fm * 16 + q * 4 + rr], s1);
          atomicAdd(&bs2[wm * 64 + fm * 16 + q * 4 + rr], s2);
        }
      }
    __syncthreads();
    if (tid < 128) {
      ps[nb * 128 + tid]          = bs1[tid];
      ps[131072 + nb * 128 + tid] = bs2[tid];
    }
  }
}

// ------- deform + fused transpose to [b][cg][i][j][16c] ----------------------
__global__ __launch_bounds__(256) void deform_t(const float* __restrict__ x,
                                                const unsigned short* __restrict__ offs,
                                                unsigned short* __restrict__ xofft) {
  __shared__ alignas(16) unsigned short t[128 * 132];
  const int i = blockIdx.x, b = blockIdx.y;
  const int tid = threadIdx.x;
  for (int e = tid; e < 16384; e += 256) {
    int c = e >> 7, j = e & 127;
    int qpix = (i << 7) + j;
    int oidx = (b << 22) + (c << 15) + 2 * qpix;   // quirky reshape semantics
    unsigned int pr = *(const unsigned int*)(offs + oidx);
    float oy = bf2f((unsigned short)(pr & 0xffffu));
    float ox = bf2f((unsigned short)(pr >> 16));
    float yc = fminf(fmaxf(oy + (float)i, 0.f), 127.f);
    float xc = fminf(fmaxf(ox + (float)j, 0.f), 127.f);
    float y0f = floorf(yc), y1f = ceilf(yc);
    float x0f = floorf(xc), x1f = ceilf(xc);
    int y0 = (int)y0f, y1 = (int)y1f, x0 = (int)x0f, x1 = (int)x1f;
    const float* img = x + ((b * C_ + c) << 14);
    float v_lt = img[y0 * W_ + x0];
    float v_rb = img[y1 * W_ + x1];
    float v_lb = img[y0 * W_ + x1];
    float v_rt = img[y1 * W_ + x0];
    float dy = yc - y0f, dx = xc - x0f;
    float v_t = v_lt + (v_rt - v_lt) * dy;
    float v_b = v_lb + (v_rb - v_lb) * dy;
    float o   = v_t + (v_b - v_t) * dx;
    t[j * 132 + c] = f2us(o);
  }
  __syncthreads();
  for (int f = tid; f < 4096; f += 256) {          // coalesced: 4 thr = 32B of one px
    int cg = f >> 9, g = f & 511;
    int j = g >> 2, c4 = (g & 3) << 2;
    uint2 v = *(const uint2*)&t[j * 132 + cg * 16 + c4];
    *(uint2*)(xofft + ((size_t)(b * 8 + cg) * HW_ + i * W_ + j) * 16 + c4) = v;
  }
}

// ---------------- BN finalize: fold stats into scale/shift -------------------
__global__ __launch_bounds__(256) void bn_finalize(const float* __restrict__ ps,
                                                   const float* __restrict__ gamma,
                                                   const float* __restrict__ beta,
                                                   float* __restrict__ stats) {
  const int c = blockIdx.x, tid = threadIdx.x;
  float s1 = 0.f, s2 = 0.f;
  for (int k = tid; k < 1024; k += 256) {
    s1 += ps[k * 128 + c];
    s2 += ps[131072 + k * 128 + c];
  }
#pragma unroll
  for (int m = 32; m > 0; m >>= 1) {
    s1 += __shfl_down(s1, m);
    s2 += __shfl_down(s2, m);
  }
  __shared__ float l1[4], l2[4];
  int wid = tid >> 6;
  if ((tid & 63) == 0) { l1[wid] = s1; l2[wid] = s2; }
  __syncthreads();
  if (tid == 0) {
    s1 = l1[0] + l1[1] + l1[2] + l1[3];
    s2 = l2[0] + l2[1] + l2[2] + l2[3];
    const float invn = 1.f / 131072.f;
    float mean = s1 * invn;
    float var  = s2 * invn - mean * mean;
    float inv  = rsqrtf(var + 1e-5f);
    float sc = gamma[c] * inv;
    stats[c]       = sc;
    stats[128 + c] = beta[c] - mean * sc;
  }
}

// ---------------- BN apply: bf16 y -> fp32 out -------------------------------
__global__ __launch_bounds__(256) void bn_apply(const unsigned short* __restrict__ y,
                                                const float* __restrict__ stats,
                                                float* __restrict__ out) {
  int gid = blockIdx.x * 256 + threadIdx.x;
  int base = gid << 3;
  int c = (base >> 14) & 127;
  float sc = stats[c], sh = stats[128 + c];
  uint4 u = *(const uint4*)(y + base);
  const unsigned short* us = (const unsigned short*)&u;
  float4 o0, o1;
  o0.x = bf2f(us[0]) * sc + sh;  o0.y = bf2f(us[1]) * sc + sh;
  o0.z = bf2f(us[2]) * sc + sh;  o0.w = bf2f(us[3]) * sc + sh;
  o1.x = bf2f(us[4]) * sc + sh;  o1.y = bf2f(us[5]) * sc + sh;
  o1.z = bf2f(us[6]) * sc + sh;  o1.w = bf2f(us[7]) * sc + sh;
  ((float4*)out)[gid * 2]     = o0;
  ((float4*)out)[gid * 2 + 1] = o1;
}

// ---------------- launch -----------------------------------------------------
extern "C" void kernel_launch(void* const* d_in, const int* in_sizes, int n_in,
                              void* d_out, int out_size, void* d_ws, size_t ws_size,
                              hipStream_t stream) {
  const float* x      = (const float*)d_in[0];
  const float* w_off  = (const float*)d_in[1];
  const float* w_conv = (const float*)d_in[2];
  const float* b_conv = (const float*)d_in[3];
  const float* gamma  = (const float*)d_in[4];
  const float* beta   = (const float*)d_in[5];
  float* out = (float*)d_out;

  char* ws = (char*)d_ws;
  unsigned short* x_t    = (unsigned short*)ws;            // 32M; dead after conv_off
  unsigned short* xoff_t = (unsigned short*)ws;            // aliases x_t
  unsigned short* offs = (unsigned short*)(ws + 33554432); // 64M
  unsigned short* yws  = (unsigned short*)(ws + 33554432); // aliases offs lo half
  float* ps    = (float*)(ws + 67108864);
  float* stats = (float*)(ws + 68157440);
  unsigned short* pack_off  = (unsigned short*)(ws + 100663296);  // 640 KB
  unsigned short* pack_main = (unsigned short*)(ws + 101318656);  // 320 KB
  char* zb = ws + 101646336;                               // 4 KB zeros

  pack_w<<<80 * 16, 256, 0, stream>>>(w_off, pack_off, (uint4*)zb, 16);
  pack_w<<<80 * 8, 256, 0, stream>>>(w_conv, pack_main, (uint4*)zb, 8);
  transpose_x<<<dim3(4, 128, 8), 256, 0, stream>>>(x, x_t);
  conv_gemm<0, 16><<<2048, 256, 0, stream>>>(x_t, pack_off, nullptr, zb, offs, nullptr);
  deform_t<<<dim3(128, 8), 256, 0, stream>>>(x, offs, xoff_t);
  conv_gemm<1, 8><<<1024, 256, 0, stream>>>(xoff_t, pack_main, b_conv, zb, yws, ps);
  bn_finalize<<<128, 256, 0, stream>>>(ps, gamma, beta, stats);
  bn_apply<<<8192, 256, 0, stream>>>(yws, stats, out);
}